// Round 19
// baseline (2714.270 us; speedup 1.0000x reference)
//
#include <hip/hip_runtime.h>
#include <cstdint>

// SelfMatchingLayer: B=32, L=512, H=256, fp32.
// R14: k7 = 1024-thread / 96-weight no-spill config with STRICT REGISTER
//      LEDGER. Diagnosis: 645us k7 carries ~1170cy/step AGPR-bounce on 192
//      weights (VALUBusy 64%/CU vs 768cy fdot2 issue). R7's attempt at this
//      config failed (VGPR=64, 849us) because its UNPACED preload (~64
//      transient regs + 96 target > 128) tripped the allocator. R14 paces:
//      preload 4 float2 in flight/gate-round; h-reads 2 uint4/sub-chunk
//      (4 sub-chunks, k-pair pp pairs w[pp] with h-word [ks*34+pp]); gi
//      staging 3 float4. Peak ~126 <= 128 cap (launch_bounds 1024,4).
//      hsbuf quarter-pad (q*34 u32): per-ks broadcast reads, conflict-free.
//      Success: VGPR>=120 & WRITE~34MB -> k7 250-400us. Fail: VGPR 64 ->
//      revert to R13 k7 (645us). k1-k6 = R13 (total 1169.9us measured).

#define LL 512
#define HH 256

typedef _Float16 half2_t __attribute__((ext_vector_type(2)));
typedef _Float16 f16x8   __attribute__((ext_vector_type(8)));
typedef float    f32x4   __attribute__((ext_vector_type(4)));

__device__ __forceinline__ float exp2f_fast(float x){
#if defined(__HIP_DEVICE_COMPILE__)
  return __builtin_amdgcn_exp2f(x);
#else
  return exp2f(x);
#endif
}
__device__ __forceinline__ float rcpf_fast(float x){
#if defined(__HIP_DEVICE_COMPILE__)
  return __builtin_amdgcn_rcpf(x);
#else
  return 1.0f/x;
#endif
}
__device__ __forceinline__ float tanh_fast(float x){
  float e = exp2f_fast(x * 2.885390081777927f);   // 2*log2(e)
  return 1.0f - 2.0f * rcpf_fast(1.0f + e);
}
__device__ __forceinline__ float sigmoid_fast(float x){
  return rcpf_fast(1.0f + exp2f_fast(x * -1.4426950408889634f));
}

#define SCALE_K2 2.885390081777927f   // 2*log2(e)

#if defined(__HIP_DEVICE_COMPILE__) && __has_builtin(__builtin_amdgcn_fdot2)
#define USE_FDOT2 1
#endif

__device__ __forceinline__ float dot2_acc(unsigned wb, unsigned hb, float a){
  half2_t wv = __builtin_bit_cast(half2_t, wb);
  half2_t hv = __builtin_bit_cast(half2_t, hb);
#ifdef USE_FDOT2
  return __builtin_amdgcn_fdot2(wv, hv, a, false);
#else
  return a + (float)wv.x*(float)hv.x + (float)wv.y*(float)hv.y;
#endif
}

__device__ __forceinline__ unsigned pack2h(float a, float b){
  half2_t h = { (_Float16)a, (_Float16)b };
  return __builtin_bit_cast(unsigned, h);
}

// ==== fp32 128x128-tile GEMM helpers (k1 only) ===========================
__device__ __forceinline__ void stage_t128(float* Ls, const float* g, int ldg){
  int tid = threadIdx.x;
  int r = tid >> 4, kq = (tid & 15) * 4;
  #pragma unroll
  for (int it = 0; it < 8; it++){
    int rr = r + 16*it;
    float4 v = *(const float4*)(g + (size_t)rr*ldg + kq);
    Ls[(kq+0)*132 + rr] = v.x;
    Ls[(kq+1)*132 + rr] = v.y;
    Ls[(kq+2)*132 + rr] = v.z;
    Ls[(kq+3)*132 + rr] = v.w;
  }
}
__device__ __forceinline__ void rg_inner128(const float* Xs, const float* Ws,
                                            float (&acc)[8][8], int rg, int cg){
  #pragma unroll 2
  for (int k = 0; k < 64; k++){
    const float* xr = Xs + k*132;
    const float* wr = Ws + k*132;
    float4 x0 = *(const float4*)(xr + rg*4);
    float4 x1 = *(const float4*)(xr + 64 + rg*4);
    float4 w0 = *(const float4*)(wr + cg*4);
    float4 w1 = *(const float4*)(wr + 64 + cg*4);
    float xv[8] = {x0.x,x0.y,x0.z,x0.w, x1.x,x1.y,x1.z,x1.w};
    float wv[8] = {w0.x,w0.y,w0.z,w0.w, w1.x,w1.y,w1.z,w1.w};
    #pragma unroll
    for (int i=0;i<8;i++)
      #pragma unroll
      for (int j=0;j<8;j++)
        acc[i][j] = fmaf(xv[i], wv[j], acc[i][j]);
  }
}
#define ROW_OF(i, rg) ((rg)*4 + ((i)&3) + ((i)>>2)*64)
#define COL_OF(j, cg) ((cg)*4 + ((j)&3) + ((j)>>2)*64)

// ==== MFMA 128x128-tile GEMM helpers (k4/k5/k6) ==========================
#define LDK 36

__device__ __forceinline__ void mstage_direct(unsigned* Ls, const float* g, int ldg){
  int tid = threadIdx.x;
  int row = tid >> 1, half = tid & 1;
  const float4* s = (const float4*)(g + (size_t)row*ldg + half*32);
  unsigned* d = Ls + row*LDK + half*16;
  #pragma unroll
  for (int i = 0; i < 8; i += 2){
    float4 a = s[i], b = s[i+1];
    uint4 o;
    o.x = pack2h(a.x,a.y); o.y = pack2h(a.z,a.w);
    o.z = pack2h(b.x,b.y); o.w = pack2h(b.z,b.w);
    *(uint4*)(d + i*2) = o;
  }
}
__device__ __forceinline__ void mstage_trans(unsigned* Ls, const float* g, int ldg){
  int tid = threadIdx.x;
  int j = (tid & 31) * 4, kq = tid >> 5;
  #pragma unroll
  for (int it = 0; it < 4; it++){
    int kp = kq*4 + it;
    float4 a = *(const float4*)(g + (size_t)(2*kp  )*ldg + j);
    float4 b = *(const float4*)(g + (size_t)(2*kp+1)*ldg + j);
    Ls[(j+0)*LDK + kp] = pack2h(a.x, b.x);
    Ls[(j+1)*LDK + kp] = pack2h(a.y, b.y);
    Ls[(j+2)*LDK + kp] = pack2h(a.z, b.z);
    Ls[(j+3)*LDK + kp] = pack2h(a.w, b.w);
  }
}
__device__ __forceinline__ void mfma_inner(const unsigned* As, const unsigned* Bs,
                                           f32x4 (&acc)[8][2], int w, int l){
  int lr = l & 15, lq = l >> 4;
  #pragma unroll
  for (int kt = 0; kt < 2; kt++){
    f16x8 bf0, bf1;
    {
      uint4 q0 = *(const uint4*)&Bs[(w*32 +      lr)*LDK + kt*16 + lq*4];
      uint4 q1 = *(const uint4*)&Bs[(w*32 + 16 + lr)*LDK + kt*16 + lq*4];
      bf0 = __builtin_bit_cast(f16x8, q0);
      bf1 = __builtin_bit_cast(f16x8, q1);
    }
    #pragma unroll
    for (int rf = 0; rf < 8; rf++){
      uint4 qa = *(const uint4*)&As[(rf*16 + lr)*LDK + kt*16 + lq*4];
      f16x8 af = __builtin_bit_cast(f16x8, qa);
      acc[rf][0] = __builtin_amdgcn_mfma_f32_16x16x32_f16(af, bf0, acc[rf][0], 0,0,0);
      acc[rf][1] = __builtin_amdgcn_mfma_f32_16x16x32_f16(af, bf1, acc[rf][1], 0,0,0);
    }
  }
}

// ---------------- K1: EH = exp2(SC*(P@wq^T+bq)) ; EP = exp2(SC*(P@wp^T+bp))
__global__ __launch_bounds__(256) void k1_hq_pp(
    const float* __restrict__ P,
    const float* __restrict__ wq_w, const float* __restrict__ wq_b,
    const float* __restrict__ wp_w, const float* __restrict__ wp_b,
    float* __restrict__ HQ, float* __restrict__ PP)
{
  __shared__ __align__(16) float Xs[64*132];
  __shared__ __align__(16) float Ws[64*132];
  int rt = blockIdx.x, ct = blockIdx.y;
  const float* W  = (ct < 2) ? wq_w : wp_w;
  const float* Bv = (ct < 2) ? wq_b : wp_b;
  float* O = (ct < 2) ? HQ : PP;
  int c0 = (ct & 1) * 128, r0 = rt * 128;
  int tid = threadIdx.x, rg = tid & 15, cg = tid >> 4;
  float acc[8][8];
  #pragma unroll
  for (int i=0;i<8;i++)
    #pragma unroll
    for (int j=0;j<8;j++) acc[i][j]=0.f;
  for (int kc = 0; kc < 4; kc++){
    __syncthreads();
    stage_t128(Xs, P + (size_t)r0*HH + kc*64, HH);
    stage_t128(Ws, W + (size_t)c0*HH + kc*64, HH);
    __syncthreads();
    rg_inner128(Xs, Ws, acc, rg, cg);
  }
  float bj[8];
  #pragma unroll
  for (int j=0;j<8;j++) bj[j] = Bv[c0 + COL_OF(j,cg)];
  #pragma unroll
  for (int i=0;i<8;i++){
    int r = r0 + ROW_OF(i,rg);
    #pragma unroll
    for (int j=0;j<8;j++)
      O[(size_t)r*HH + c0 + COL_OF(j,cg)] =
          exp2f_fast(SCALE_K2 * (acc[i][j] + bj[j]));
  }
}

// ---------------- K2: scores + FUSED softmax ------------------------------
__global__ __launch_bounds__(256) void k2_scores(
    const float* __restrict__ HQ, const float* __restrict__ PP,
    const float* __restrict__ ws_w, float* __restrict__ S)
{
  __shared__ float Hq_c[128*65];
  __shared__ float Pp_c[32*65];
  __shared__ float wsl[256];
  int tid = threadIdx.x;
  int b = blockIdx.y, t0 = blockIdx.x * 32;
  wsl[tid] = ws_w[tid];
  int tg = tid >> 6;
  int lg = tid & 63;
  float acc4[4][8][2];
  #pragma unroll
  for (int lc=0;lc<4;lc++)
    #pragma unroll
    for (int i=0;i<8;i++){ acc4[lc][i][0]=0.f; acc4[lc][i][1]=0.f; }
  #pragma unroll
  for (int lc = 0; lc < 4; lc++){
    #pragma unroll 1
    for (int hc = 0; hc < 4; hc++){
      __syncthreads();
      {
        int r = tid >> 4, kq = (tid & 15) * 4;
        #pragma unroll
        for (int it=0; it<2; it++){
          int t = r + 16*it;
          float4 v = *(const float4*)(PP + ((size_t)b*LL + t0 + t)*HH + hc*64 + kq);
          float* d = Pp_c + t*65 + kq;
          d[0]=v.x; d[1]=v.y; d[2]=v.z; d[3]=v.w;
        }
      }
      {
        int r = tid >> 4, kq = (tid & 15) * 4;
        #pragma unroll
        for (int it=0; it<8; it++){
          int l = r + 16*it;
          float4 v = *(const float4*)(HQ + ((size_t)b*LL + lc*128 + l)*HH + hc*64 + kq);
          float* d = Hq_c + l*65 + kq;
          d[0]=v.x; d[1]=v.y; d[2]=v.z; d[3]=v.w;
        }
      }
      __syncthreads();
      #pragma unroll 2
      for (int h = 0; h < 64; h++){
        float w = wsl[hc*64 + h];
        float pp[8], hq[2];
        #pragma unroll
        for (int i=0;i<8;i++) pp[i] = Pp_c[(tg + 4*i)*65 + h];
        #pragma unroll
        for (int j=0;j<2;j++) hq[j] = Hq_c[(2*lg + j)*65 + h];
        #pragma unroll
        for (int i=0;i<8;i++)
          #pragma unroll
          for (int j=0;j<2;j++){
            float e = pp[i] * hq[j];                 // exp2 pre-hoisted (k1)
            acc4[lc][i][j] = fmaf(w, rcpf_fast(1.0f + e), acc4[lc][i][j]);
          }
      }
    }
  }
  #pragma unroll
  for (int i=0;i<8;i++){
    float v[8];
    #pragma unroll
    for (int lc=0;lc<4;lc++){
      v[lc*2+0] = -2.0f*acc4[lc][i][0];
      v[lc*2+1] = -2.0f*acc4[lc][i][1];
    }
    float m = v[0];
    #pragma unroll
    for (int k=1;k<8;k++) m = fmaxf(m, v[k]);
    #pragma unroll
    for (int off=32; off>=1; off>>=1) m = fmaxf(m, __shfl_xor(m, off, 64));
    float s = 0.f;
    #pragma unroll
    for (int k=0;k<8;k++){ v[k] = exp2f_fast((v[k]-m)*1.4426950408889634f); s += v[k]; }
    #pragma unroll
    for (int off=32; off>=1; off>>=1) s += __shfl_xor(s, off, 64);
    float inv = 1.0f / s;
    size_t base = ((size_t)b*LL + t0 + tg + 4*i)*LL;
    #pragma unroll
    for (int lc=0;lc<4;lc++){
      S[base + lc*128 + 2*lg + 0] = v[lc*2+0]*inv;
      S[base + lc*128 + 2*lg + 1] = v[lc*2+1]*inv;
    }
  }
}

// ---------------- K4: C[b,t,:] = attn[b,t,:] @ P[b,:,:] (MFMA) ------------
__global__ __launch_bounds__(256, 4) void k4_context(
    const float* __restrict__ S, const float* __restrict__ P, float* __restrict__ C)
{
  __shared__ __align__(16) unsigned As[128*LDK];
  __shared__ __align__(16) unsigned Bs[128*LDK];
  int j0 = blockIdx.x * 128, t0 = blockIdx.y * 128, b = blockIdx.z;
  int tid = threadIdx.x, w = tid >> 6, l = tid & 63;
  f32x4 acc[8][2];
  #pragma unroll
  for (int i=0;i<8;i++){ acc[i][0]=(f32x4){0,0,0,0}; acc[i][1]=(f32x4){0,0,0,0}; }
  for (int lc = 0; lc < 8; lc++){
    int l0 = lc*64;
    __syncthreads();
    mstage_direct(As, S + ((size_t)b*LL + t0)*LL + l0, LL);
    mstage_trans (Bs, P + ((size_t)b*LL + l0)*HH + j0, HH);
    __syncthreads();
    mfma_inner(As, Bs, acc, w, l);
  }
  int lr = l & 15, lq = l >> 4;
  #pragma unroll
  for (int rf=0; rf<8; rf++)
    #pragma unroll
    for (int cf=0; cf<2; cf++){
      int col = j0 + w*32 + cf*16 + lr;
      #pragma unroll
      for (int r=0; r<4; r++){
        int row = t0 + rf*16 + lq*4 + r;
        C[((size_t)b*LL + row)*HH + col] = acc[rf][cf][r];
      }
    }
}

// ---------------- K5: Cg = sigmoid([P|C]@wg^T + bg) * C (MFMA) ------------
__global__ __launch_bounds__(256, 4) void k5_gate(
    const float* __restrict__ P, const float* __restrict__ C,
    const float* __restrict__ wg_w, const float* __restrict__ wg_b,
    float* __restrict__ CG)
{
  __shared__ __align__(16) unsigned As[128*LDK];
  __shared__ __align__(16) unsigned Bs[128*LDK];
  int r0 = blockIdx.x*128, c0 = blockIdx.y*128;
  int tid = threadIdx.x, w = tid >> 6, l = tid & 63;
  f32x4 acc[8][2];
  #pragma unroll
  for (int i=0;i<8;i++){ acc[i][0]=(f32x4){0,0,0,0}; acc[i][1]=(f32x4){0,0,0,0}; }
  for (int kc = 0; kc < 8; kc++){
    const float* Xsrc = (kc < 4) ? (P + (size_t)r0*HH + kc*64)
                                 : (C + (size_t)r0*HH + (kc-4)*64);
    __syncthreads();
    mstage_direct(As, Xsrc, HH);
    mstage_direct(Bs, wg_w + (size_t)c0*(2*HH) + kc*64, 2*HH);
    __syncthreads();
    mfma_inner(As, Bs, acc, w, l);
  }
  int lr = l & 15, lq = l >> 4;
  #pragma unroll
  for (int cf=0; cf<2; cf++){
    int col = c0 + w*32 + cf*16 + lr;
    float bj = wg_b[col];
    #pragma unroll
    for (int rf=0; rf<8; rf++)
      #pragma unroll
      for (int r=0; r<4; r++){
        int row = r0 + rf*16 + lq*4 + r;
        float g = sigmoid_fast(acc[rf][cf][r] + bj);
        CG[(size_t)row*HH + col] = g * C[(size_t)row*HH + col];
      }
  }
}

// ---------------- K6: GI_{l,r} = Cg @ Wih^T + bih (MFMA) ------------------
__global__ __launch_bounds__(256, 4) void k6_gi(
    const float* __restrict__ CG,
    const float* __restrict__ Wih_l, const float* __restrict__ bih_l,
    const float* __restrict__ Wih_r, const float* __restrict__ bih_r,
    float* __restrict__ GIL, float* __restrict__ GIR)
{
  __shared__ __align__(16) unsigned As[128*LDK];
  __shared__ __align__(16) unsigned Bs[128*LDK];
  int rt = blockIdx.x, ct = blockIdx.y;
  int dir = (ct >= 6);
  const float* Wih = dir ? Wih_r : Wih_l;
  const float* bih = dir ? bih_r : bih_l;
  float* GI = dir ? GIR : GIL;
  int c0 = (ct % 6) * 128, r0 = rt * 128;
  int tid = threadIdx.x, w = tid >> 6, l = tid & 63;
  f32x4 acc[8][2];
  #pragma unroll
  for (int i=0;i<8;i++){ acc[i][0]=(f32x4){0,0,0,0}; acc[i][1]=(f32x4){0,0,0,0}; }
  for (int kc = 0; kc < 4; kc++){
    __syncthreads();
    mstage_direct(As, CG  + (size_t)r0*HH + kc*64, HH);
    mstage_direct(Bs, Wih + (size_t)c0*HH + kc*64, HH);
    __syncthreads();
    mfma_inner(As, Bs, acc, w, l);
  }
  int lr = l & 15, lq = l >> 4;
  #pragma unroll
  for (int cf=0; cf<2; cf++){
    int col = c0 + w*32 + cf*16 + lr;
    float bj = bih[col];
    #pragma unroll
    for (int rf=0; rf<8; rf++)
      #pragma unroll
      for (int r=0; r<4; r++){
        int row = r0 + rf*16 + lq*4 + r;
        GI[(size_t)row*768 + col] = acc[rf][cf][r] + bj;
      }
  }
}

// ---------------- K7: GRU scans (R14: 1024 thr, 96 wgt, paced) ------------
// 64 blocks (b,dir) x 1024 threads. Thread t: u = t>>2, ks = t&3, k0=ks*64.
// w_{r,z,n}[pp] (k-pair pp = quarter k 2pp,2pp+1) pairs with h-word
// hsbuf[s&1][ks*34+pp]. 4 paced sub-chunks x 8 k-pairs (2 uint4 in flight).
// 2-stage shfl reduce over ks bits; GRU redundant on 4 lanes; one barrier
// per step; hsbuf quarter-pad (q*34 u32) -> per-ks broadcast, no conflicts.
__global__ __launch_bounds__(1024, 4) void k7_scan(
    const float* __restrict__ GIL, const float* __restrict__ GIR,
    const float* __restrict__ Whh_l, const float* __restrict__ bhh_l,
    const float* __restrict__ Whh_r, const float* __restrict__ bhh_r,
    float* __restrict__ out)
{
  int b   = blockIdx.x >> 1;
  int dir = blockIdx.x & 1;
  int t   = threadIdx.x;
  int u   = t >> 2;          // output dim 0..255
  int ks  = t & 3;           // k quarter
  int k0  = ks * 64;
  const float* GI  = dir ? GIR : GIL;
  const float* Whh = dir ? Whh_r : Whh_l;
  const float* bhh = dir ? bhh_r : bhh_l;

  // Weights rows u, u+256, u+512 over k0..k0+63: 32 u32 each; paced.
  unsigned w_r[32], w_z[32], w_n[32];
  {
    const float2* wr = (const float2*)(Whh + (size_t)(u      )*HH + k0);
    const float2* wz = (const float2*)(Whh + (size_t)(u + 256)*HH + k0);
    const float2* wn = (const float2*)(Whh + (size_t)(u + 512)*HH + k0);
    #pragma unroll
    for (int pc = 0; pc < 8; pc++){
      #pragma unroll
      for (int p = pc*4; p < pc*4+4; p++){ float2 a = wr[p]; w_r[p] = pack2h(a.x, a.y); }
      __builtin_amdgcn_sched_barrier(0);
      #pragma unroll
      for (int p = pc*4; p < pc*4+4; p++){ float2 a = wz[p]; w_z[p] = pack2h(a.x, a.y); }
      __builtin_amdgcn_sched_barrier(0);
      #pragma unroll
      for (int p = pc*4; p < pc*4+4; p++){ float2 a = wn[p]; w_n[p] = pack2h(a.x, a.y); }
      __builtin_amdgcn_sched_barrier(0);
    }
  }
  float b_r = bhh[u], b_z = bhh[u + 256], b_n = bhh[u + 512];

  __shared__ __align__(16) unsigned hsbuf[2][136];   // quarter q at q*34 u32
  __shared__ __align__(16) float gi_buf[32*768];     // 96 KB
  __shared__ __align__(16) float out_buf[32*256];    // 32 KB
  if (t < 136){ hsbuf[0][t] = 0; }

  float hprev = 0.f;

  #pragma unroll 1
  for (int chunk = 0; chunk < 16; chunk++){
    int s0 = chunk * 32;
    int tlo = dir ? (LL - s0 - 32) : s0;    // staged t range [tlo, tlo+31]
    // stage 32 steps of gi: 6144 float4 over 1024 threads; paced 3-in-flight
    {
      const float4* src = (const float4*)(GI + ((size_t)b*LL + tlo)*768);
      float4* dst = (float4*)gi_buf;
      #pragma unroll
      for (int rd = 0; rd < 2; rd++){
        float4 v0 = src[t + 1024*(3*rd+0)];
        float4 v1 = src[t + 1024*(3*rd+1)];
        float4 v2 = src[t + 1024*(3*rd+2)];
        dst[t + 1024*(3*rd+0)] = v0;
        dst[t + 1024*(3*rd+1)] = v1;
        dst[t + 1024*(3*rd+2)] = v2;
        __builtin_amdgcn_sched_barrier(0);
      }
    }
    __syncthreads();   // gi_buf ready; hs writes from prev step visible

    #pragma unroll 1
    for (int p = 0; p < 32; p++){
      int s = s0 + p;
      int tt = dir ? (LL-1-s) : s;
      int gidx = tt - tlo;                  // 0..31
      float ar0=0.f, ar1=0.f, az0=0.f, az1=0.f, an0=0.f, an1=0.f;
      // 4 paced sub-chunks of 8 k-pairs: 2 uint4 h-words in flight each
      #pragma unroll
      for (int sc = 0; sc < 4; sc++){
        const uint4* hp = (const uint4*)(hsbuf[s & 1] + ks*34) + sc*2;
        uint4 q0 = hp[0], q1 = hp[1];
        unsigned hv[8] = {q0.x,q0.y,q0.z,q0.w, q1.x,q1.y,q1.z,q1.w};
        #pragma unroll
        for (int j = 0; j < 8; j += 2){
          int pp = sc*8 + j;
          ar0 = dot2_acc(w_r[pp  ], hv[j  ], ar0);
          az0 = dot2_acc(w_z[pp  ], hv[j  ], az0);
          an0 = dot2_acc(w_n[pp  ], hv[j  ], an0);
          ar1 = dot2_acc(w_r[pp+1], hv[j+1], ar1);
          az1 = dot2_acc(w_z[pp+1], hv[j+1], az1);
          an1 = dot2_acc(w_n[pp+1], hv[j+1], an1);
        }
        __builtin_amdgcn_sched_barrier(0);
      }
      float ar = ar0 + ar1, az = az0 + az1, an = an0 + an1;
      // combine 4 k-quarters (ks = lane bits 0..1): xor-1 then xor-2
      ar += __shfl_xor(ar, 1, 64);
      az += __shfl_xor(az, 1, 64);
      an += __shfl_xor(an, 1, 64);
      ar += __shfl_xor(ar, 2, 64);
      az += __shfl_xor(az, 2, 64);
      an += __shfl_xor(an, 2, 64);
      const float* g = gi_buf + (size_t)gidx*768;
      float r  = sigmoid_fast(g[u      ] + ar + b_r);
      float z  = sigmoid_fast(g[u + 256] + az + b_z);
      float n  = tanh_fast  (g[u + 512] + r*(an + b_n));
      float hn = z*(hprev - n) + n;
      hprev = hn;
      if (ks == 0){
        out_buf[p*256 + u] = hn;
        ((unsigned short*)hsbuf[(s & 1) ^ 1])[(u >> 6)*68 + (u & 63)] =
            __builtin_bit_cast(unsigned short, (_Float16)hn);
      }
      __syncthreads();   // hs(write-buf) ready; separates reads from next writes
    }
    // flush outputs (coalesced 256-wide per step); 8 per thread paced
    #pragma unroll
    for (int fr = 0; fr < 2; fr++){
      #pragma unroll
      for (int q = 0; q < 4; q++){
        int i = t + 1024*(fr*4 + q);
        int p = i >> 8, uu = i & 255;
        int s = s0 + p;
        int tt = dir ? (LL-1-s) : s;
        out[((size_t)b*LL + tt)*(2*HH) + dir*HH + uu] = out_buf[i];
      }
      __builtin_amdgcn_sched_barrier(0);
    }
    __syncthreads();   // out_buf/gi_buf safe to reuse
  }
}

extern "C" void kernel_launch(void* const* d_in, const int* in_sizes, int n_in,
                              void* d_out, int out_size, void* d_ws, size_t ws_size,
                              hipStream_t stream)
{
  const float* P    = (const float*)d_in[0];
  const float* wq_w = (const float*)d_in[1];
  const float* wq_b = (const float*)d_in[2];
  const float* wp_w = (const float*)d_in[3];
  const float* wp_b = (const float*)d_in[4];
  const float* ws_w = (const float*)d_in[5];
  // d_in[6] = ws_b: softmax-invariant, unused
  const float* wg_w = (const float*)d_in[7];
  const float* wg_b = (const float*)d_in[8];
  const float* Wih_l= (const float*)d_in[9];
  const float* Whh_l= (const float*)d_in[10];
  const float* bih_l= (const float*)d_in[11];
  const float* bhh_l= (const float*)d_in[12];
  const float* Wih_r= (const float*)d_in[13];
  const float* Whh_r= (const float*)d_in[14];
  const float* bih_r= (const float*)d_in[15];
  const float* bhh_r= (const float*)d_in[16];

  float* ws  = (float*)d_ws;
  float* HQ  = ws;                    //  4,194,304
  float* PP  = ws + 4194304;          //  4,194,304
  float* S   = ws + 8388608;          //  8,388,608
  float* C   = ws + 16777216;         //  4,194,304
  float* CG  = ws + 20971520;         //  4,194,304
  float* GIR = ws + 25165824;         // 12,582,912
  float* GIL = ws;                    // 12,582,912 (aliases HQ/PP/S-front; dead by k6)
  float* out = (float*)d_out;

  k1_hq_pp  <<<dim3(128, 4),    256, 0, stream>>>(P, wq_w, wq_b, wp_w, wp_b, HQ, PP);
  k2_scores <<<dim3(16, 32),    256, 0, stream>>>(HQ, PP, ws_w, S);
  k4_context<<<dim3(2, 4, 32),  256, 0, stream>>>(S, P, C);
  k5_gate   <<<dim3(128, 2),    256, 0, stream>>>(P, C, wg_w, wg_b, CG);
  k6_gi     <<<dim3(128, 12),   256, 0, stream>>>(CG, Wih_l, bih_l, Wih_r, bih_r, GIL, GIR);
  k7_scan   <<<64,             1024, 0, stream>>>(GIL, GIR, Whh_l, bhh_l, Whh_r, bhh_r, out);
}

// Round 21
// 1174.039 us; speedup vs baseline: 2.3119x; 2.3119x over previous
//
#include <hip/hip_runtime.h>
#include <cstdint>

// SelfMatchingLayer: B=32, L=512, H=256, fp32.
// R16 = R13 (measured 1169.9us) + S-as-fp16. k4 is S's only consumer and
//      immediately converts fp32->fp16 in staging; moving the pack2h into
//      k2's store is BIT-IDENTICAL (same rounding, same (even,odd) l
//      pairing) while halving S HBM traffic (33.5+33.5 -> 16.8+16.8 MB)
//      and making k4's A-stage a pure uint4 copy. Everything else
//      unchanged: k1 exp2-epilogue, k2 fused softmax, MFMA k4/k5/k6,
//      R8-k7 (645us, CLOSED: R7/R14 refuted >=96-weight configs, R9/R10
//      refuted MFMA-k7).

#define LL 512
#define HH 256

typedef _Float16 half2_t __attribute__((ext_vector_type(2)));
typedef _Float16 f16x8   __attribute__((ext_vector_type(8)));
typedef float    f32x4   __attribute__((ext_vector_type(4)));

__device__ __forceinline__ float exp2f_fast(float x){
#if defined(__HIP_DEVICE_COMPILE__)
  return __builtin_amdgcn_exp2f(x);
#else
  return exp2f(x);
#endif
}
__device__ __forceinline__ float rcpf_fast(float x){
#if defined(__HIP_DEVICE_COMPILE__)
  return __builtin_amdgcn_rcpf(x);
#else
  return 1.0f/x;
#endif
}
__device__ __forceinline__ float tanh_fast(float x){
  float e = exp2f_fast(x * 2.885390081777927f);   // 2*log2(e)
  return 1.0f - 2.0f * rcpf_fast(1.0f + e);
}
__device__ __forceinline__ float sigmoid_fast(float x){
  return rcpf_fast(1.0f + exp2f_fast(x * -1.4426950408889634f));
}

#define SCALE_K2 2.885390081777927f   // 2*log2(e)

#if defined(__HIP_DEVICE_COMPILE__) && __has_builtin(__builtin_amdgcn_fdot2)
#define USE_FDOT2 1
#endif

__device__ __forceinline__ float dot2_acc(unsigned wb, unsigned hb, float a){
  half2_t wv = __builtin_bit_cast(half2_t, wb);
  half2_t hv = __builtin_bit_cast(half2_t, hb);
#ifdef USE_FDOT2
  return __builtin_amdgcn_fdot2(wv, hv, a, false);
#else
  return a + (float)wv.x*(float)hv.x + (float)wv.y*(float)hv.y;
#endif
}

__device__ __forceinline__ unsigned pack2h(float a, float b){
  half2_t h = { (_Float16)a, (_Float16)b };
  return __builtin_bit_cast(unsigned, h);
}

// ==== fp32 128x128-tile GEMM helpers (k1 only) ===========================
__device__ __forceinline__ void stage_t128(float* Ls, const float* g, int ldg){
  int tid = threadIdx.x;
  int r = tid >> 4, kq = (tid & 15) * 4;
  #pragma unroll
  for (int it = 0; it < 8; it++){
    int rr = r + 16*it;
    float4 v = *(const float4*)(g + (size_t)rr*ldg + kq);
    Ls[(kq+0)*132 + rr] = v.x;
    Ls[(kq+1)*132 + rr] = v.y;
    Ls[(kq+2)*132 + rr] = v.z;
    Ls[(kq+3)*132 + rr] = v.w;
  }
}
__device__ __forceinline__ void rg_inner128(const float* Xs, const float* Ws,
                                            float (&acc)[8][8], int rg, int cg){
  #pragma unroll 2
  for (int k = 0; k < 64; k++){
    const float* xr = Xs + k*132;
    const float* wr = Ws + k*132;
    float4 x0 = *(const float4*)(xr + rg*4);
    float4 x1 = *(const float4*)(xr + 64 + rg*4);
    float4 w0 = *(const float4*)(wr + cg*4);
    float4 w1 = *(const float4*)(wr + 64 + cg*4);
    float xv[8] = {x0.x,x0.y,x0.z,x0.w, x1.x,x1.y,x1.z,x1.w};
    float wv[8] = {w0.x,w0.y,w0.z,w0.w, w1.x,w1.y,w1.z,w1.w};
    #pragma unroll
    for (int i=0;i<8;i++)
      #pragma unroll
      for (int j=0;j<8;j++)
        acc[i][j] = fmaf(xv[i], wv[j], acc[i][j]);
  }
}
#define ROW_OF(i, rg) ((rg)*4 + ((i)&3) + ((i)>>2)*64)
#define COL_OF(j, cg) ((cg)*4 + ((j)&3) + ((j)>>2)*64)

// ==== MFMA 128x128-tile GEMM helpers (k4/k5/k6) ==========================
#define LDK 36

__device__ __forceinline__ void mstage_direct(unsigned* Ls, const float* g, int ldg){
  int tid = threadIdx.x;
  int row = tid >> 1, half = tid & 1;
  const float4* s = (const float4*)(g + (size_t)row*ldg + half*32);
  unsigned* d = Ls + row*LDK + half*16;
  #pragma unroll
  for (int i = 0; i < 8; i += 2){
    float4 a = s[i], b = s[i+1];
    uint4 o;
    o.x = pack2h(a.x,a.y); o.y = pack2h(a.z,a.w);
    o.z = pack2h(b.x,b.y); o.w = pack2h(b.z,b.w);
    *(uint4*)(d + i*2) = o;
  }
}
// pure fp16 copy (k4 A: S already stored as fp16 pairs) -------------------
__device__ __forceinline__ void mstage_copy_h(unsigned* Ls, const unsigned* g, int ldg_u32){
  int tid = threadIdx.x;
  int row = tid >> 1, half = tid & 1;
  const uint4* s = (const uint4*)(g + (size_t)row*ldg_u32 + half*16);
  uint4* d = (uint4*)(Ls + row*LDK + half*16);
  #pragma unroll
  for (int i = 0; i < 4; i++) d[i] = s[i];
}
__device__ __forceinline__ void mstage_trans(unsigned* Ls, const float* g, int ldg){
  int tid = threadIdx.x;
  int j = (tid & 31) * 4, kq = tid >> 5;
  #pragma unroll
  for (int it = 0; it < 4; it++){
    int kp = kq*4 + it;
    float4 a = *(const float4*)(g + (size_t)(2*kp  )*ldg + j);
    float4 b = *(const float4*)(g + (size_t)(2*kp+1)*ldg + j);
    Ls[(j+0)*LDK + kp] = pack2h(a.x, b.x);
    Ls[(j+1)*LDK + kp] = pack2h(a.y, b.y);
    Ls[(j+2)*LDK + kp] = pack2h(a.z, b.z);
    Ls[(j+3)*LDK + kp] = pack2h(a.w, b.w);
  }
}
__device__ __forceinline__ void mfma_inner(const unsigned* As, const unsigned* Bs,
                                           f32x4 (&acc)[8][2], int w, int l){
  int lr = l & 15, lq = l >> 4;
  #pragma unroll
  for (int kt = 0; kt < 2; kt++){
    f16x8 bf0, bf1;
    {
      uint4 q0 = *(const uint4*)&Bs[(w*32 +      lr)*LDK + kt*16 + lq*4];
      uint4 q1 = *(const uint4*)&Bs[(w*32 + 16 + lr)*LDK + kt*16 + lq*4];
      bf0 = __builtin_bit_cast(f16x8, q0);
      bf1 = __builtin_bit_cast(f16x8, q1);
    }
    #pragma unroll
    for (int rf = 0; rf < 8; rf++){
      uint4 qa = *(const uint4*)&As[(rf*16 + lr)*LDK + kt*16 + lq*4];
      f16x8 af = __builtin_bit_cast(f16x8, qa);
      acc[rf][0] = __builtin_amdgcn_mfma_f32_16x16x32_f16(af, bf0, acc[rf][0], 0,0,0);
      acc[rf][1] = __builtin_amdgcn_mfma_f32_16x16x32_f16(af, bf1, acc[rf][1], 0,0,0);
    }
  }
}

// ---------------- K1: EH = exp2(SC*(P@wq^T+bq)) ; EP = exp2(SC*(P@wp^T+bp))
__global__ __launch_bounds__(256) void k1_hq_pp(
    const float* __restrict__ P,
    const float* __restrict__ wq_w, const float* __restrict__ wq_b,
    const float* __restrict__ wp_w, const float* __restrict__ wp_b,
    float* __restrict__ HQ, float* __restrict__ PP)
{
  __shared__ __align__(16) float Xs[64*132];
  __shared__ __align__(16) float Ws[64*132];
  int rt = blockIdx.x, ct = blockIdx.y;
  const float* W  = (ct < 2) ? wq_w : wp_w;
  const float* Bv = (ct < 2) ? wq_b : wp_b;
  float* O = (ct < 2) ? HQ : PP;
  int c0 = (ct & 1) * 128, r0 = rt * 128;
  int tid = threadIdx.x, rg = tid & 15, cg = tid >> 4;
  float acc[8][8];
  #pragma unroll
  for (int i=0;i<8;i++)
    #pragma unroll
    for (int j=0;j<8;j++) acc[i][j]=0.f;
  for (int kc = 0; kc < 4; kc++){
    __syncthreads();
    stage_t128(Xs, P + (size_t)r0*HH + kc*64, HH);
    stage_t128(Ws, W + (size_t)c0*HH + kc*64, HH);
    __syncthreads();
    rg_inner128(Xs, Ws, acc, rg, cg);
  }
  float bj[8];
  #pragma unroll
  for (int j=0;j<8;j++) bj[j] = Bv[c0 + COL_OF(j,cg)];
  #pragma unroll
  for (int i=0;i<8;i++){
    int r = r0 + ROW_OF(i,rg);
    #pragma unroll
    for (int j=0;j<8;j++)
      O[(size_t)r*HH + c0 + COL_OF(j,cg)] =
          exp2f_fast(SCALE_K2 * (acc[i][j] + bj[j]));
  }
}

// ---------------- K2: scores + FUSED softmax, fp16 S out ------------------
// S_eff[b,t,l] = -2 * sum_h w_h / (1 + EH[b,l,h]*EP[b,t,h]); softmax over l
// in-register; store S as fp16 pairs (u32 = halves (2lg, 2lg+1)).
__global__ __launch_bounds__(256) void k2_scores(
    const float* __restrict__ HQ, const float* __restrict__ PP,
    const float* __restrict__ ws_w, unsigned* __restrict__ Sh)
{
  __shared__ float Hq_c[128*65];
  __shared__ float Pp_c[32*65];
  __shared__ float wsl[256];
  int tid = threadIdx.x;
  int b = blockIdx.y, t0 = blockIdx.x * 32;
  wsl[tid] = ws_w[tid];
  int tg = tid >> 6;
  int lg = tid & 63;
  float acc4[4][8][2];
  #pragma unroll
  for (int lc=0;lc<4;lc++)
    #pragma unroll
    for (int i=0;i<8;i++){ acc4[lc][i][0]=0.f; acc4[lc][i][1]=0.f; }
  #pragma unroll
  for (int lc = 0; lc < 4; lc++){
    #pragma unroll 1
    for (int hc = 0; hc < 4; hc++){
      __syncthreads();
      {
        int r = tid >> 4, kq = (tid & 15) * 4;
        #pragma unroll
        for (int it=0; it<2; it++){
          int t = r + 16*it;
          float4 v = *(const float4*)(PP + ((size_t)b*LL + t0 + t)*HH + hc*64 + kq);
          float* d = Pp_c + t*65 + kq;
          d[0]=v.x; d[1]=v.y; d[2]=v.z; d[3]=v.w;
        }
      }
      {
        int r = tid >> 4, kq = (tid & 15) * 4;
        #pragma unroll
        for (int it=0; it<8; it++){
          int l = r + 16*it;
          float4 v = *(const float4*)(HQ + ((size_t)b*LL + lc*128 + l)*HH + hc*64 + kq);
          float* d = Hq_c + l*65 + kq;
          d[0]=v.x; d[1]=v.y; d[2]=v.z; d[3]=v.w;
        }
      }
      __syncthreads();
      #pragma unroll 2
      for (int h = 0; h < 64; h++){
        float w = wsl[hc*64 + h];
        float pp[8], hq[2];
        #pragma unroll
        for (int i=0;i<8;i++) pp[i] = Pp_c[(tg + 4*i)*65 + h];
        #pragma unroll
        for (int j=0;j<2;j++) hq[j] = Hq_c[(2*lg + j)*65 + h];
        #pragma unroll
        for (int i=0;i<8;i++)
          #pragma unroll
          for (int j=0;j<2;j++){
            float e = pp[i] * hq[j];                 // exp2 pre-hoisted (k1)
            acc4[lc][i][j] = fmaf(w, rcpf_fast(1.0f + e), acc4[lc][i][j]);
          }
      }
    }
  }
  #pragma unroll
  for (int i=0;i<8;i++){
    float v[8];
    #pragma unroll
    for (int lc=0;lc<4;lc++){
      v[lc*2+0] = -2.0f*acc4[lc][i][0];
      v[lc*2+1] = -2.0f*acc4[lc][i][1];
    }
    float m = v[0];
    #pragma unroll
    for (int k=1;k<8;k++) m = fmaxf(m, v[k]);
    #pragma unroll
    for (int off=32; off>=1; off>>=1) m = fmaxf(m, __shfl_xor(m, off, 64));
    float s = 0.f;
    #pragma unroll
    for (int k=0;k<8;k++){ v[k] = exp2f_fast((v[k]-m)*1.4426950408889634f); s += v[k]; }
    #pragma unroll
    for (int off=32; off>=1; off>>=1) s += __shfl_xor(s, off, 64);
    float inv = 1.0f / s;
    size_t baseh = ((size_t)b*LL + t0 + tg + 4*i)*(LL/2);
    #pragma unroll
    for (int lc=0;lc<4;lc++)
      Sh[baseh + lc*64 + lg] = pack2h(v[lc*2+0]*inv, v[lc*2+1]*inv);
  }
}

// ---------------- K4: C[b,t,:] = attn[b,t,:] @ P[b,:,:] (MFMA) ------------
// A = S (fp16 in memory): pure copy stage. B = P transpose-packed.
__global__ __launch_bounds__(256, 4) void k4_context(
    const unsigned* __restrict__ Sh, const float* __restrict__ P, float* __restrict__ C)
{
  __shared__ __align__(16) unsigned As[128*LDK];
  __shared__ __align__(16) unsigned Bs[128*LDK];
  int j0 = blockIdx.x * 128, t0 = blockIdx.y * 128, b = blockIdx.z;
  int tid = threadIdx.x, w = tid >> 6, l = tid & 63;
  f32x4 acc[8][2];
  #pragma unroll
  for (int i=0;i<8;i++){ acc[i][0]=(f32x4){0,0,0,0}; acc[i][1]=(f32x4){0,0,0,0}; }
  for (int lc = 0; lc < 8; lc++){
    int l0 = lc*64;
    __syncthreads();
    mstage_copy_h(As, Sh + ((size_t)b*LL + t0)*(LL/2) + l0/2, LL/2);
    mstage_trans (Bs, P + ((size_t)b*LL + l0)*HH + j0, HH);
    __syncthreads();
    mfma_inner(As, Bs, acc, w, l);
  }
  int lr = l & 15, lq = l >> 4;
  #pragma unroll
  for (int rf=0; rf<8; rf++)
    #pragma unroll
    for (int cf=0; cf<2; cf++){
      int col = j0 + w*32 + cf*16 + lr;
      #pragma unroll
      for (int r=0; r<4; r++){
        int row = t0 + rf*16 + lq*4 + r;
        C[((size_t)b*LL + row)*HH + col] = acc[rf][cf][r];
      }
    }
}

// ---------------- K5: Cg = sigmoid([P|C]@wg^T + bg) * C (MFMA) ------------
__global__ __launch_bounds__(256, 4) void k5_gate(
    const float* __restrict__ P, const float* __restrict__ C,
    const float* __restrict__ wg_w, const float* __restrict__ wg_b,
    float* __restrict__ CG)
{
  __shared__ __align__(16) unsigned As[128*LDK];
  __shared__ __align__(16) unsigned Bs[128*LDK];
  int r0 = blockIdx.x*128, c0 = blockIdx.y*128;
  int tid = threadIdx.x, w = tid >> 6, l = tid & 63;
  f32x4 acc[8][2];
  #pragma unroll
  for (int i=0;i<8;i++){ acc[i][0]=(f32x4){0,0,0,0}; acc[i][1]=(f32x4){0,0,0,0}; }
  for (int kc = 0; kc < 8; kc++){
    const float* Xsrc = (kc < 4) ? (P + (size_t)r0*HH + kc*64)
                                 : (C + (size_t)r0*HH + (kc-4)*64);
    __syncthreads();
    mstage_direct(As, Xsrc, HH);
    mstage_direct(Bs, wg_w + (size_t)c0*(2*HH) + kc*64, 2*HH);
    __syncthreads();
    mfma_inner(As, Bs, acc, w, l);
  }
  int lr = l & 15, lq = l >> 4;
  #pragma unroll
  for (int cf=0; cf<2; cf++){
    int col = c0 + w*32 + cf*16 + lr;
    float bj = wg_b[col];
    #pragma unroll
    for (int rf=0; rf<8; rf++)
      #pragma unroll
      for (int r=0; r<4; r++){
        int row = r0 + rf*16 + lq*4 + r;
        float g = sigmoid_fast(acc[rf][cf][r] + bj);
        CG[(size_t)row*HH + col] = g * C[(size_t)row*HH + col];
      }
  }
}

// ---------------- K6: GI_{l,r} = Cg @ Wih^T + bih (MFMA) ------------------
__global__ __launch_bounds__(256, 4) void k6_gi(
    const float* __restrict__ CG,
    const float* __restrict__ Wih_l, const float* __restrict__ bih_l,
    const float* __restrict__ Wih_r, const float* __restrict__ bih_r,
    float* __restrict__ GIL, float* __restrict__ GIR)
{
  __shared__ __align__(16) unsigned As[128*LDK];
  __shared__ __align__(16) unsigned Bs[128*LDK];
  int rt = blockIdx.x, ct = blockIdx.y;
  int dir = (ct >= 6);
  const float* Wih = dir ? Wih_r : Wih_l;
  const float* bih = dir ? bih_r : bih_l;
  float* GI = dir ? GIR : GIL;
  int c0 = (ct % 6) * 128, r0 = rt * 128;
  int tid = threadIdx.x, w = tid >> 6, l = tid & 63;
  f32x4 acc[8][2];
  #pragma unroll
  for (int i=0;i<8;i++){ acc[i][0]=(f32x4){0,0,0,0}; acc[i][1]=(f32x4){0,0,0,0}; }
  for (int kc = 0; kc < 4; kc++){
    __syncthreads();
    mstage_direct(As, CG  + (size_t)r0*HH + kc*64, HH);
    mstage_direct(Bs, Wih + (size_t)c0*HH + kc*64, HH);
    __syncthreads();
    mfma_inner(As, Bs, acc, w, l);
  }
  int lr = l & 15, lq = l >> 4;
  #pragma unroll
  for (int cf=0; cf<2; cf++){
    int col = c0 + w*32 + cf*16 + lr;
    float bj = bih[col];
    #pragma unroll
    for (int rf=0; rf<8; rf++)
      #pragma unroll
      for (int r=0; r<4; r++){
        int row = r0 + rf*16 + lq*4 + r;
        GI[(size_t)row*768 + col] = acc[rf][cf][r] + bj;
      }
  }
}

// ---------------- K7: GRU scans (R8 fdot2; measured 645us; CLOSED) --------
__global__ __launch_bounds__(512, 2) void k7_scan(
    const float* __restrict__ GIL, const float* __restrict__ GIR,
    const float* __restrict__ Whh_l, const float* __restrict__ bhh_l,
    const float* __restrict__ Whh_r, const float* __restrict__ bhh_r,
    float* __restrict__ out)
{
  int b   = blockIdx.x >> 1;
  int dir = blockIdx.x & 1;
  int t   = threadIdx.x;
  int u   = t >> 1;          // output dim 0..255
  int ks  = t & 1;           // k half
  int k0  = ks * 128;
  const float* GI  = dir ? GIR : GIL;
  const float* Whh = dir ? Whh_r : Whh_l;
  const float* bhh = dir ? bhh_r : bhh_l;

  unsigned w_r[64], w_z[64], w_n[64];
  {
    const float2* wr = (const float2*)(Whh + (size_t)(u      )*HH + k0);
    const float2* wz = (const float2*)(Whh + (size_t)(u + 256)*HH + k0);
    const float2* wn = (const float2*)(Whh + (size_t)(u + 512)*HH + k0);
    #pragma unroll
    for (int pc = 0; pc < 8; pc++){
      #pragma unroll
      for (int p = pc*8; p < pc*8+8; p++){ float2 a = wr[p]; w_r[p] = pack2h(a.x, a.y); }
      __builtin_amdgcn_sched_barrier(0);
      #pragma unroll
      for (int p = pc*8; p < pc*8+8; p++){ float2 a = wz[p]; w_z[p] = pack2h(a.x, a.y); }
      __builtin_amdgcn_sched_barrier(0);
      #pragma unroll
      for (int p = pc*8; p < pc*8+8; p++){ float2 a = wn[p]; w_n[p] = pack2h(a.x, a.y); }
      __builtin_amdgcn_sched_barrier(0);
    }
  }
  float b_r = bhh[u], b_z = bhh[u + 256], b_n = bhh[u + 512];

  __shared__ __align__(16) unsigned hsbuf[2][128];   // fp16 h, ping-pong
  __shared__ __align__(16) float gi_buf[32*768];     // 96 KB
  __shared__ __align__(16) float out_buf[32*256];    // 32 KB
  if (t < 128){ hsbuf[0][t] = 0; }

  float hprev = 0.f;

  #pragma unroll 1
  for (int chunk = 0; chunk < 16; chunk++){
    int s0 = chunk * 32;
    int tlo = dir ? (LL - s0 - 32) : s0;    // staged t range [tlo, tlo+31]
    {
      const float4* src = (const float4*)(GI + ((size_t)b*LL + tlo)*768);
      float4* dst = (float4*)gi_buf;
      #pragma unroll
      for (int rd = 0; rd < 3; rd++){
        float4 v0 = src[t + 512*(4*rd+0)];
        float4 v1 = src[t + 512*(4*rd+1)];
        float4 v2 = src[t + 512*(4*rd+2)];
        float4 v3 = src[t + 512*(4*rd+3)];
        dst[t + 512*(4*rd+0)] = v0;
        dst[t + 512*(4*rd+1)] = v1;
        dst[t + 512*(4*rd+2)] = v2;
        dst[t + 512*(4*rd+3)] = v3;
        __builtin_amdgcn_sched_barrier(0);
      }
    }
    __syncthreads();   // gi_buf ready; hs writes from prev step visible

    #pragma unroll 1
    for (int p = 0; p < 32; p++){
      int s = s0 + p;
      int tt = dir ? (LL-1-s) : s;
      int gidx = tt - tlo;                  // 0..31
      float ar0=0.f, ar1=0.f, az0=0.f, az1=0.f, an0=0.f, an1=0.f;
      #pragma unroll
      for (int sc = 0; sc < 4; sc++){
        const uint4* hp = (const uint4*)(hsbuf[s & 1]) + ks*16 + sc*4;
        uint4 q0 = hp[0], q1 = hp[1], q2 = hp[2], q3 = hp[3];
        unsigned hv[16] = {q0.x,q0.y,q0.z,q0.w, q1.x,q1.y,q1.z,q1.w,
                           q2.x,q2.y,q2.z,q2.w, q3.x,q3.y,q3.z,q3.w};
        #pragma unroll
        for (int j = 0; j < 16; j += 2){
          int pp = sc*16 + j;
          ar0 = dot2_acc(w_r[pp  ], hv[j  ], ar0);
          az0 = dot2_acc(w_z[pp  ], hv[j  ], az0);
          an0 = dot2_acc(w_n[pp  ], hv[j  ], an0);
          ar1 = dot2_acc(w_r[pp+1], hv[j+1], ar1);
          az1 = dot2_acc(w_z[pp+1], hv[j+1], az1);
          an1 = dot2_acc(w_n[pp+1], hv[j+1], an1);
        }
        __builtin_amdgcn_sched_barrier(0);
      }
      float ar = ar0 + ar1, az = az0 + az1, an = an0 + an1;
      ar += __shfl_xor(ar, 1, 64);
      az += __shfl_xor(az, 1, 64);
      an += __shfl_xor(an, 1, 64);
      const float* g = gi_buf + (size_t)gidx*768;
      float r  = sigmoid_fast(g[u      ] + ar + b_r);
      float z  = sigmoid_fast(g[u + 256] + az + b_z);
      float n  = tanh_fast  (g[u + 512] + r*(an + b_n));
      float hn = z*(hprev - n) + n;
      hprev = hn;
      if (ks == 0){
        out_buf[p*256 + u] = hn;
        ((unsigned short*)hsbuf[(s & 1) ^ 1])[u] =
            __builtin_bit_cast(unsigned short, (_Float16)hn);
      }
      __syncthreads();   // hs(write-buf) ready; separates reads from next writes
    }
    #pragma unroll
    for (int fr = 0; fr < 4; fr++){
      #pragma unroll
      for (int q = 0; q < 4; q++){
        int i = t + 512*(fr*4 + q);
        int p = i >> 8, uu = i & 255;
        int s = s0 + p;
        int tt = dir ? (LL-1-s) : s;
        out[((size_t)b*LL + tt)*(2*HH) + dir*HH + uu] = out_buf[i];
      }
      __builtin_amdgcn_sched_barrier(0);
    }
    __syncthreads();   // out_buf/gi_buf safe to reuse
  }
}

extern "C" void kernel_launch(void* const* d_in, const int* in_sizes, int n_in,
                              void* d_out, int out_size, void* d_ws, size_t ws_size,
                              hipStream_t stream)
{
  const float* P    = (const float*)d_in[0];
  const float* wq_w = (const float*)d_in[1];
  const float* wq_b = (const float*)d_in[2];
  const float* wp_w = (const float*)d_in[3];
  const float* wp_b = (const float*)d_in[4];
  const float* ws_w = (const float*)d_in[5];
  // d_in[6] = ws_b: softmax-invariant, unused
  const float* wg_w = (const float*)d_in[7];
  const float* wg_b = (const float*)d_in[8];
  const float* Wih_l= (const float*)d_in[9];
  const float* Whh_l= (const float*)d_in[10];
  const float* bih_l= (const float*)d_in[11];
  const float* bhh_l= (const float*)d_in[12];
  const float* Wih_r= (const float*)d_in[13];
  const float* Whh_r= (const float*)d_in[14];
  const float* bih_r= (const float*)d_in[15];
  const float* bhh_r= (const float*)d_in[16];

  float* ws  = (float*)d_ws;
  float* HQ  = ws;                    //  4,194,304
  float* PP  = ws + 4194304;          //  4,194,304
  unsigned* Sh = (unsigned*)(ws + 8388608);  // S as fp16 pairs: 4,194,304 u32
  float* C   = ws + 16777216;         //  4,194,304
  float* CG  = ws + 20971520;         //  4,194,304
  float* GIR = ws + 25165824;         // 12,582,912
  float* GIL = ws;                    // 12,582,912 (aliases HQ/PP/Sh; dead by k6)
  float* out = (float*)d_out;

  k1_hq_pp  <<<dim3(128, 4),    256, 0, stream>>>(P, wq_w, wq_b, wp_w, wp_b, HQ, PP);
  k2_scores <<<dim3(16, 32),    256, 0, stream>>>(HQ, PP, ws_w, Sh);
  k4_context<<<dim3(2, 4, 32),  256, 0, stream>>>(Sh, P, C);
  k5_gate   <<<dim3(128, 2),    256, 0, stream>>>(P, C, wg_w, wg_b, CG);
  k6_gi     <<<dim3(128, 12),   256, 0, stream>>>(CG, Wih_l, bih_l, Wih_r, bih_r, GIL, GIR);
  k7_scan   <<<64,              512, 0, stream>>>(GIL, GIR, Whh_l, bhh_l, Whh_r, bhh_r, out);
}